// Round 5
// baseline (779.348 us; speedup 1.0000x reference)
//
#include <hip/hip_runtime.h>
#include <math.h>

#define NN 500
#define BB 512
#define ISPL 2             // i-split: each block owns a 250-wide i-band
#define IPAIR (NN / 2)     // 250 i-pairs per row
#define IBP (IPAIR / ISPL) // 125 i-pairs per block
#define JP 2               // j-parity split across thread halves

using f2 = __attribute__((ext_vector_type(2))) float;

// ---------------- prep: bit-exact f32 threshold + interleaved (W,U*) table ---
// Emulate numpy's float32 pipeline with correctly-rounded f32 ops:
//   uc -> l1=f32(log uc); s=f32(1-uc); l2=f32(log s);
//   z=f32(la+f32(l1-l2)); y=f32(1/f32(1+f32(exp(-z)))); decision = y > 0.5f
__device__ __forceinline__ bool np_decision(float laf, float v) {
    float l1 = (float)log((double)v);
    float s  = 1.0f - v;
    float l2 = (float)log((double)s);
    float logistic = l1 - l2;
    float z  = laf + logistic;
    float e  = (float)exp(-(double)z);
    float d  = 1.0f + e;
    float y  = 1.0f / d;
    return y > 0.5f;
}

// WU[j*NN+i] = { Wt, Ustar } where Wt = (i==j ? 0 : W[i][j]) and Ustar is the
// smallest f32 uc in [LO,HI] whose emulated-f32 decision is TRUE (monotone).
// Comparing RAW u >= Ustar reproduces the clamped semantics exactly:
//   Ustar=0   -> always true  (u>=0)
//   Ustar=inf -> never true
//   middle    -> u<LO => clamp->LO, decision(LO)=false, and u<LO<=Ustar: false;
//                u>HI => clamp->HI, decision(HI)=true,  and u>HI>=Ustar: true.
__global__ void prep_kernel(const float* __restrict__ la,
                            const float* __restrict__ W,
                            float2* __restrict__ WU) {
    int idx = blockIdx.x * blockDim.x + threadIdx.x;
    if (idx >= NN * NN) return;
    int j = idx / NN;
    int i = idx - j * NN;
    float laf = la[idx];

    const float LO = 1e-6f;
    const float HI = (float)(1.0 - 1e-6);

    float U;
    if (!np_decision(laf, HI)) {
        U = __builtin_inff();               // never true
    } else if (np_decision(laf, LO)) {
        U = 0.0f;                           // always true
    } else {
        // invariant: decision(lo)==false, decision(hi)==true
        unsigned lo = __float_as_uint(LO);
        unsigned hi = __float_as_uint(HI);
        double T  = 1.0 / (1.0 + exp((double)laf));
        float  Tf = fminf(fmaxf((float)T, LO), HI);
        unsigned g = __float_as_uint(Tf);
        unsigned a = (g > lo + 8u) ? g - 8u : lo;
        unsigned b = (g + 8u < hi) ? g + 8u : hi;
        if (a > lo) {
            if (np_decision(laf, __uint_as_float(a))) hi = a; else lo = a;
        }
        if (b > lo && b < hi) {
            if (np_decision(laf, __uint_as_float(b))) hi = b; else lo = b;
        }
        while (hi - lo > 1u) {
            unsigned mid = lo + (hi - lo) / 2u;
            if (np_decision(laf, __uint_as_float(mid))) hi = mid; else lo = mid;
        }
        U = __uint_as_float(hi);
    }
    float w = (i == j) ? 0.0f : W[i * NN + j];
    WU[idx] = make_float2(w, U);
}

// ---------------- fused: full-j masked matvec for one (b, i-band) ------------
// grid = BB * ISPL = 1024 blocks of 256 threads (4 blocks/CU, 16 waves/CU).
// Thread (tj, tp): tj = j-parity (waves 0-1 vs 2-3), tp = i-pair in the band.
// Per iter: one nt f2 u load (8B/lane, 512B/wave contiguous) + one float4
// WU load (L2-resident) + predicated FMA pair. j-reduction completes inside
// the block (1 KB LDS combine of the two parities) -> tanh written straight
// to out. No P buffer, no reduce kernel, no inter-block protocol.
__global__ __launch_bounds__(256) void fused_kernel(
        const float* __restrict__ x,
        const float* __restrict__ u,
        const float2* __restrict__ WU,
        float* __restrict__ out) {
    __shared__ float xs[NN];
    __shared__ float2 red[128];
    const int bid = blockIdx.x;
    const int b   = bid >> 1;          // batch row
    const int ic  = bid & 1;           // i-band
    const int i0p = ic * IBP;          // first i-pair of band
    const int t  = threadIdx.x;
    const int tj = t >> 7;             // j parity
    const int tp = t & 127;            // i-pair within band (125 active)

    for (int o = t; o < NN; o += 256) xs[o] = x[b * NN + o];
    __syncthreads();

    float a0 = 0.0f, a1 = 0.0f;
    if (tp < IBP) {
        const f2* __restrict__ up  = (const f2*)(u + (size_t)b * NN * NN);
        const float4* __restrict__ wu4 = (const float4*)WU;
        int k = tj * IPAIR + i0p + tp;   // same f2/f4 row-major index for u/WU
#pragma unroll 10
        for (int js = 0; js < NN / JP; ++js) {
            f2     v  = __builtin_nontemporal_load(up + k);
            float4 wv = wu4[k];                    // (w0, U0, w1, U1)
            float  xj = xs[js * JP + tj];
            if (v.x >= wv.y) a0 += wv.x * xj;
            if (v.y >= wv.w) a1 += wv.z * xj;
            k += JP * IPAIR;
        }
    }

    if (tj) red[tp] = make_float2(a0, a1);
    __syncthreads();
    if (!tj && tp < IBP) {
        float2 r = red[tp];
        float2 o = make_float2(tanhf(a0 + r.x), tanhf(a1 + r.y));
        ((float2*)(out + b * NN + 2 * i0p))[tp] = o;
    }
}

extern "C" void kernel_launch(void* const* d_in, const int* in_sizes, int n_in,
                              void* d_out, int out_size, void* d_ws, size_t ws_size,
                              hipStream_t stream) {
    const float* x  = (const float*)d_in[0];   // [B, N]
    const float* la = (const float*)d_in[1];   // [N, N]
    const float* W  = (const float*)d_in[2];   // [N, N]
    const float* u  = (const float*)d_in[3];   // [B, N, N]
    float* out = (float*)d_out;                // [B, N]

    float2* WU = (float2*)d_ws;                // 2,000,000 B

    int prep_blocks = (NN * NN + 255) / 256;
    prep_kernel<<<prep_blocks, 256, 0, stream>>>(la, W, WU);
    fused_kernel<<<BB * ISPL, 256, 0, stream>>>(x, u, WU, out);
}